// Round 8
// baseline (369.303 us; speedup 1.0000x reference)
//
#include <hip/hip_runtime.h>
#include <stdint.h>

#define TWO_PI_F 6.28318530717958647692f
#define INV_2PI_F 0.15915494309189535f
#define EPSF 1e-6f
#define DTF 0.01f
#define KCOUP 2.0f
#define CPL (DTF * KCOUP * INV_2PI_F)   // coupling gain in revolutions domain

// ---- GEMM geometry ----
#define BM 128
#define BN 96
#define KITERS 32                 // 2048 / 64
#define NTILES 7                  // 672 / 96, exact
#define B_TILE_BYTES (BN * 128)   // 12288 (96 cols x 128B per 64-K chunk)
#define WCHUNK (672 * 128)        // 86016 bytes per K-chunk of B image
#define W_IMG_BYTES ((size_t)KITERS * WCHUNK)   // 2,752,512
#define WS_NEED W_IMG_BYTES

typedef __attribute__((ext_vector_type(8)))  __bf16         bf16x8;
typedef __attribute__((ext_vector_type(8)))  unsigned short ushort8v;
typedef __attribute__((ext_vector_type(16))) float          f32x16;

__device__ __forceinline__ unsigned short f2bf(float f) {
  unsigned u = __builtin_bit_cast(unsigned, f);
  u = (u + 0x7FFFu + ((u >> 16) & 1u)) >> 16;   // RNE
  return (unsigned short)u;
}

// pack 2 f32 -> 2 bf16 (RNE, hw default round), S0 -> low16, S1 -> high16
__device__ __forceinline__ unsigned cvtpk(float lo, float hi) {
  unsigned r;
  asm("v_cvt_pk_bf16_f32 %0, %1, %2" : "=v"(r) : "v"(lo), "v"(hi));
  return r;
}

// ---------- prep_w: W (f32) -> swizzled bf16 image [t][col][slot*16B] ----------
__global__ void prep_w(const float* __restrict__ Wd, const float* __restrict__ Wt,
                       const float* __restrict__ Wg, char* __restrict__ wbB) {
  int id = blockIdx.x * 256 + threadIdx.x;      // 672 * 64 total
  if (id >= 672 * 64) return;
  int col = id >> 6;
  int rem = id & 63, t = rem >> 1, h = rem & 1;
  const float* src = (col < 32)  ? Wd + (size_t)col * 2048
                   : (col < 160) ? Wt + (size_t)(col - 32) * 2048
                                 : Wg + (size_t)(col - 160) * 2048;
  src += t * 64 + h * 32;
  char* dst = wbB + ((size_t)t * 672 + col) * 128;
  #pragma unroll
  for (int s4 = 0; s4 < 4; s4++) {
    float4 a = ((const float4*)src)[s4 * 2];
    float4 b = ((const float4*)src)[s4 * 2 + 1];
    ushort8v v;
    v[0] = f2bf(a.x); v[1] = f2bf(a.y); v[2] = f2bf(a.z); v[3] = f2bf(a.w);
    v[4] = f2bf(b.x); v[5] = f2bf(b.y); v[6] = f2bf(b.z); v[7] = f2bf(b.w);
    int slot = (h * 4 + s4) ^ (col & 7);
    *(ushort8v*)(dst + slot * 16) = v;
  }
}

// ---------- K1: fused f32-A gemm. A: global->reg->cvt (no LDS). B: gll dbuf ----------
__launch_bounds__(256, 4)
__global__ void gemm_f(const float* __restrict__ x, const char* __restrict__ wbB,
                       float* __restrict__ z) {
  __shared__ __align__(16) char smem[2 * B_TILE_BYTES];   // 24 KB

  const int tid = threadIdx.x;
  const int wid = tid >> 6, lane = tid & 63;

  // XCD-aware: each XCD owns exclusive row panels; 7 n-tiles of a panel adjacent
  const int bid = blockIdx.x;
  const int xcd = bid & 7, j = bid >> 3;
  const int panel = xcd * ((gridDim.x / NTILES) >> 3) + j / NTILES;
  const int n = j % NTILES;
  const size_t row0 = (size_t)panel * BM;

  f32x16 acc[3];
  #pragma unroll
  for (int f = 0; f < 3; f++)
    #pragma unroll
    for (int jj = 0; jj < 16; jj++) acc[f][jj] = 0.f;

  const char* bsrc0 = wbB + n * B_TILE_BYTES;
  // A source: wave's row = row0 + wid*32 + (lane&31); k-half offset (lane>>5)*8.
  // MFMA s4 fragment needs k = t*64 + s4*16 + hk*8 .. +7  (slot map sl = s4*2+hk).
  const float* abase = x + (row0 + wid * 32 + (lane & 31)) * 2048 + (lane >> 5) * 8;

#define STAGE_B(buf, t)                                                       \
  { const char* bsrc = bsrc0 + (size_t)(t) * WCHUNK;                          \
    _Pragma("unroll")                                                         \
    for (int rnd = 0; rnd < 3; rnd++) {                                       \
      int off = rnd * 4096 + tid * 16;                                        \
      __builtin_amdgcn_global_load_lds(                                       \
        (const __attribute__((address_space(1))) void*)(bsrc + off),          \
        (__attribute__((address_space(3))) void*)(smem + (buf) * B_TILE_BYTES + off), \
        16, 0, 0); } }

// per s4: 8 floats at t*64 + s4*16 (+ hk*8 already in abase)  [FIXED layout]
#define LOADA(t)                                                              \
  { _Pragma("unroll")                                                         \
    for (int s4 = 0; s4 < 4; s4++) {                                          \
      const float4* ap = (const float4*)(abase + (t) * 64 + s4 * 16);         \
      aF[s4 * 2] = ap[0]; aF[s4 * 2 + 1] = ap[1]; } }

#define CVTA()                                                                \
  { _Pragma("unroll")                                                         \
    for (int s4 = 0; s4 < 4; s4++) {                                          \
      unsigned d0 = cvtpk(aF[s4*2].x, aF[s4*2].y);                            \
      unsigned d1 = cvtpk(aF[s4*2].z, aF[s4*2].w);                            \
      unsigned d2 = cvtpk(aF[s4*2+1].x, aF[s4*2+1].y);                        \
      unsigned d3 = cvtpk(aF[s4*2+1].z, aF[s4*2+1].w);                        \
      uint4 u = {d0, d1, d2, d3};                                             \
      abf[s4] = __builtin_bit_cast(bf16x8, u); } }

  float4 aF[8];
  bf16x8 abf[4];
  LOADA(0);
  STAGE_B(0, 0);

  for (int t = 0; t < KITERS; t++) {
    const int cur = t & 1;
    if (t + 1 < KITERS) {
      STAGE_B(cur ^ 1, t + 1);                 // 3 gll for next tile
      CVTA();                                  // implicit wait retires A(t) AND B(t)
      LOADA(t + 1);                            // 8 f32 loads for next tile
      asm volatile("s_waitcnt vmcnt(11)" ::: "memory");   // next tile stays in flight
    } else {
      CVTA();
      asm volatile("s_waitcnt vmcnt(0)" ::: "memory");
    }
    __builtin_amdgcn_s_barrier();              // tile t staged & visible to all waves
    __builtin_amdgcn_sched_barrier(0);

    const char* Bs = smem + cur * B_TILE_BYTES;
    #pragma unroll
    for (int s4 = 0; s4 < 4; s4++) {
      int sl = s4 * 2 + (lane >> 5);
      #pragma unroll
      for (int fn = 0; fn < 3; fn++) {
        int c = fn * 32 + (lane & 31);
        bf16x8 bfr = __builtin_bit_cast(bf16x8,
            *(const ushort8v*)(Bs + c * 128 + ((sl ^ (c & 7)) << 4)));
        acc[fn] = __builtin_amdgcn_mfma_f32_32x32x16_bf16(abf[s4], bfr, acc[fn], 0, 0, 0);
      }
    }
    __builtin_amdgcn_sched_barrier(0);
    __builtin_amdgcn_s_barrier();              // all reads of buf done before re-stage
  }
#undef STAGE_B
#undef LOADA
#undef CVTA

  #pragma unroll
  for (int fn = 0; fn < 3; fn++) {
    int col = n * 96 + fn * 32 + (lane & 31);
    #pragma unroll
    for (int reg = 0; reg < 16; reg++) {
      int row = wid * 32 + (reg & 3) + ((reg >> 2) << 3) + ((lane >> 5) << 2);
      z[(row0 + row) * 672 + col] = acc[fn][reg];
    }
  }
}

// ---------- K2: Kuramoto dynamics + in-place scale of d_out ----------
#define ZSTR 164
#define DROWS 32
__launch_bounds__(256, 6)
__global__ void dyn_scale(float* __restrict__ z,
                          const float* __restrict__ pdt_p,
                          const float* __restrict__ ptg_p) {
  __shared__ float zdt[DROWS * ZSTR];
  __shared__ float Fbuf[2 * DROWS];
  const int tid = threadIdx.x;
  const int wid = tid >> 6, lane = tid & 63;
  const size_t row0 = (size_t)blockIdx.x * DROWS;

  for (int i = tid; i < DROWS * 40; i += 256) {
    int row = i / 40, c4 = i - row * 40;
    float4 v = *(const float4*)(z + (row0 + row) * 672 + c4 * 4);
    *(float4*)(&zdt[row * ZSTR + c4 * 4]) = v;
  }
  __syncthreads();

  const float pdt = fminf(fmaxf(pdt_p[0], 0.f), 1.f);
  const float ptg = fminf(fmaxf(ptg_p[0], 0.f), 1.f);

  for (int rr = 0; rr < 8; rr++) {
    int row = wid * 8 + rr;
    // phases in revolutions: q = p / 2π;  sin(p) = v_sin(fract(q))
    float pd  = ((lane < 32) ? zdt[row * ZSTR + lane] : 0.f) * INV_2PI_F;
    float pt0 = zdt[row * ZSTR + 32 + lane] * INV_2PI_F;
    float pt1 = zdt[row * ZSTR + 96 + lane] * INV_2PI_F;
    float Ft = 1.f, Fg = 1.f;
    for (int s = 0; s < 10; s++) {
      float qd = pd - floorf(pd), q0 = pt0 - floorf(pt0), q1 = pt1 - floorf(pt1);
      float sd, cd, s0, c0, s1, c1;
      asm("v_sin_f32 %0, %1" : "=v"(sd) : "v"(qd));
      asm("v_cos_f32 %0, %1" : "=v"(cd) : "v"(qd));
      asm("v_sin_f32 %0, %1" : "=v"(s0) : "v"(q0));
      asm("v_cos_f32 %0, %1" : "=v"(c0) : "v"(q0));
      asm("v_sin_f32 %0, %1" : "=v"(s1) : "v"(q1));
      asm("v_cos_f32 %0, %1" : "=v"(c1) : "v"(q1));
      float vCd = (lane < 32) ? cd : 0.f;
      float vSd = (lane < 32) ? sd : 0.f;
      float vCt = c0 + c1, vSt = s0 + s1;
      #pragma unroll
      for (int off = 32; off > 0; off >>= 1) {
        vCd += __shfl_xor(vCd, off);
        vSd += __shfl_xor(vSd, off);
        vCt += __shfl_xor(vCt, off);
        vSt += __shfl_xor(vSt, off);
      }
      float Cd = vCd * (1.f / 32.f),  Sd = vSd * (1.f / 32.f);
      float Ct = vCt * (1.f / 128.f), St = vSt * (1.f / 128.f);
      // q_{n+1} = q + DT*F + (DT*K/2π)(S*cos − C*sin)   [mod 1 via fract at use]
      pd  += DTF * 2.f + CPL * (Sd * cd - Cd * sd);
      pt0 += DTF * 6.f + CPL * (St * c0 - Ct * s0);
      pt1 += DTF * 6.f + CPL * (St * c1 - Ct * s1);
      float rdm = sqrtf(Cd * Cd + Sd * Sd) + EPSF;
      float rtm = sqrtf(Ct * Ct + St * St) + EPSF;
      Ft *= (1.f + DTF * pdt * (Cd / rdm));
      Fg *= (1.f + DTF * ptg * (Ct / rtm));
    }
    if (lane == 0) { Fbuf[row] = Ft; Fbuf[DROWS + row] = Fg; }
  }
  __syncthreads();

  for (int i = tid; i < DROWS * 168; i += 256) {
    int row = i / 168, c4 = i - row * 168;
    float4* p = (float4*)(z + (row0 + row) * 672 + c4 * 4);
    float4 v = *p;
    float f = (c4 < 8) ? 1.f : (c4 < 40 ? Fbuf[row] : Fbuf[DROWS + row]);
    v.x = fmaxf(fmaxf(fabsf(v.x), EPSF) * f, EPSF);
    v.y = fmaxf(fmaxf(fabsf(v.y), EPSF) * f, EPSF);
    v.z = fmaxf(fmaxf(fabsf(v.z), EPSF) * f, EPSF);
    v.w = fmaxf(fmaxf(fabsf(v.w), EPSF) * f, EPSF);
    *p = v;
  }
}

extern "C" void kernel_launch(void* const* d_in, const int* in_sizes, int n_in,
                              void* d_out, int out_size, void* d_ws, size_t ws_size,
                              hipStream_t stream) {
  const float* x   = (const float*)d_in[0];
  const float* Wd  = (const float*)d_in[1];
  const float* Wt  = (const float*)d_in[2];
  const float* Wg  = (const float*)d_in[3];
  const float* pdt = (const float*)d_in[4];
  const float* ptg = (const float*)d_in[5];
  float* outp = (float*)d_out;
  char* wbB = (char*)d_ws;

  if (ws_size < WS_NEED) return;

  const int Brows = in_sizes[0] / 2048;           // 32768
  prep_w<<<(672 * 64 + 255) / 256, 256, 0, stream>>>(Wd, Wt, Wg, wbB);
  gemm_f<<<(Brows / BM) * NTILES, 256, 0, stream>>>(x, wbB, outp);
  dyn_scale<<<Brows / DROWS, 256, 0, stream>>>(outp, pdt, ptg);
}

// Round 9
// 348.901 us; speedup vs baseline: 1.0585x; 1.0585x over previous
//
#include <hip/hip_runtime.h>
#include <stdint.h>

#define TWO_PI_F 6.28318530717958647692f
#define INV_2PI_F 0.15915494309189535f
#define EPSF 1e-6f
#define DTF 0.01f
#define KCOUP 2.0f
#define CPL (DTF * KCOUP * INV_2PI_F)   // coupling gain in revolutions domain

// ---- GEMM geometry ----
#define BM 128
#define BN 96
#define KITERS 32                 // 2048 / 64
#define NTILES 7                  // 672 / 96, exact
#define B_TILE_BYTES (BN * 128)   // 12288 (96 cols x 128B per 64-K chunk)
#define WCHUNK (672 * 128)        // 86016 bytes per K-chunk of B image
#define W_IMG_BYTES ((size_t)KITERS * WCHUNK)   // 2,752,512
#define WS_NEED W_IMG_BYTES

typedef __attribute__((ext_vector_type(8)))  __bf16         bf16x8;
typedef __attribute__((ext_vector_type(8)))  unsigned short ushort8v;
typedef __attribute__((ext_vector_type(16))) float          f32x16;

__device__ __forceinline__ unsigned short f2bf(float f) {
  unsigned u = __builtin_bit_cast(unsigned, f);
  u = (u + 0x7FFFu + ((u >> 16) & 1u)) >> 16;   // RNE
  return (unsigned short)u;
}

// pack 2 f32 -> 2 bf16 (RNE), S0 -> low16, S1 -> high16
__device__ __forceinline__ unsigned cvtpk(float lo, float hi) {
  unsigned r;
  asm("v_cvt_pk_bf16_f32 %0, %1, %2" : "=v"(r) : "v"(lo), "v"(hi));
  return r;
}

// ---------- prep_w: W (f32) -> swizzled bf16 image [t][col][slot*16B] ----------
__global__ void prep_w(const float* __restrict__ Wd, const float* __restrict__ Wt,
                       const float* __restrict__ Wg, char* __restrict__ wbB) {
  int id = blockIdx.x * 256 + threadIdx.x;      // 672 * 64 total
  if (id >= 672 * 64) return;
  int col = id >> 6;
  int rem = id & 63, t = rem >> 1, h = rem & 1;
  const float* src = (col < 32)  ? Wd + (size_t)col * 2048
                   : (col < 160) ? Wt + (size_t)(col - 32) * 2048
                                 : Wg + (size_t)(col - 160) * 2048;
  src += t * 64 + h * 32;
  char* dst = wbB + ((size_t)t * 672 + col) * 128;
  #pragma unroll
  for (int s4 = 0; s4 < 4; s4++) {
    float4 a = ((const float4*)src)[s4 * 2];
    float4 b = ((const float4*)src)[s4 * 2 + 1];
    ushort8v v;
    v[0] = f2bf(a.x); v[1] = f2bf(a.y); v[2] = f2bf(a.z); v[3] = f2bf(a.w);
    v[4] = f2bf(b.x); v[5] = f2bf(b.y); v[6] = f2bf(b.z); v[7] = f2bf(b.w);
    int slot = (h * 4 + s4) ^ (col & 7);
    *(ushort8v*)(dst + slot * 16) = v;
  }
}

// ---------- K1: f32-A gemm, 2-iteration-deep pipeline, one vmcnt(11)/iter ----------
__launch_bounds__(256, 3)
__global__ void gemm_f(const float* __restrict__ x, const char* __restrict__ wbB,
                       float* __restrict__ z) {
  __shared__ __align__(16) char smem[2 * B_TILE_BYTES];   // 24 KB

  const int tid = threadIdx.x;
  const int wid = tid >> 6, lane = tid & 63;

  const int bid = blockIdx.x;
  const int xcd = bid & 7, j = bid >> 3;
  const int panel = xcd * ((gridDim.x / NTILES) >> 3) + j / NTILES;
  const int n = j % NTILES;
  const size_t row0 = (size_t)panel * BM;

  f32x16 acc[3];
  #pragma unroll
  for (int f = 0; f < 3; f++)
    #pragma unroll
    for (int jj = 0; jj < 16; jj++) acc[f][jj] = 0.f;

  const char* bsrc0 = wbB + n * B_TILE_BYTES;
  // A source: row = row0 + wid*32 + (lane&31); k-half offset (lane>>5)*8.
  // MFMA s4 fragment: k = t*64 + s4*16 + hk*8 .. +7  (slot sl = s4*2+hk).
  const float* abase = x + (row0 + wid * 32 + (lane & 31)) * 2048 + (lane >> 5) * 8;

#define STAGE_B(buf, t)                                                       \
  { const char* bsrc = bsrc0 + (size_t)(t) * WCHUNK;                          \
    _Pragma("unroll")                                                         \
    for (int rnd = 0; rnd < 3; rnd++) {                                       \
      int off = rnd * 4096 + tid * 16;                                        \
      __builtin_amdgcn_global_load_lds(                                       \
        (const __attribute__((address_space(1))) void*)(bsrc + off),          \
        (__attribute__((address_space(3))) void*)(smem + (buf) * B_TILE_BYTES + off), \
        16, 0, 0); } }

#define LOADA(arr, t)                                                         \
  { _Pragma("unroll")                                                         \
    for (int s4 = 0; s4 < 4; s4++) {                                          \
      const float4* ap = (const float4*)(abase + (t) * 64 + s4 * 16);         \
      arr[s4 * 2] = ap[0]; arr[s4 * 2 + 1] = ap[1]; } }

#define CVTA(arr)                                                             \
  { _Pragma("unroll")                                                         \
    for (int s4 = 0; s4 < 4; s4++) {                                          \
      unsigned d0 = cvtpk(arr[s4*2].x, arr[s4*2].y);                          \
      unsigned d1 = cvtpk(arr[s4*2].z, arr[s4*2].w);                          \
      unsigned d2 = cvtpk(arr[s4*2+1].x, arr[s4*2+1].y);                      \
      unsigned d3 = cvtpk(arr[s4*2+1].z, arr[s4*2+1].w);                      \
      uint4 u = {d0, d1, d2, d3};                                             \
      abf[s4] = __builtin_bit_cast(bf16x8, u); } }

#define MFMA12(cur)                                                           \
  { const char* Bs = smem + (cur) * B_TILE_BYTES;                             \
    _Pragma("unroll")                                                         \
    for (int s4 = 0; s4 < 4; s4++) {                                          \
      int sl = s4 * 2 + (lane >> 5);                                          \
      _Pragma("unroll")                                                       \
      for (int fn = 0; fn < 3; fn++) {                                        \
        int c = fn * 32 + (lane & 31);                                        \
        bf16x8 bfr = __builtin_bit_cast(bf16x8,                               \
            *(const ushort8v*)(Bs + c * 128 + ((sl ^ (c & 7)) << 4)));        \
        acc[fn] = __builtin_amdgcn_mfma_f32_32x32x16_bf16(abf[s4], bfr, acc[fn], 0, 0, 0); } } }

// One iteration: AL = reg-buffer to load A(t+2) into (holds dead A(t) f32);
//                AC = reg-buffer holding A(t+1) f32 (convert after compute).
#define BODY(t, AL, AC, cur)                                                  \
  {                                                                           \
    if ((t) + 2 < KITERS) { LOADA(AL, (t) + 2); }                             \
    if ((t) >= KITERS - 2) { asm volatile("s_waitcnt vmcnt(0)" ::: "memory"); } \
    else                   { asm volatile("s_waitcnt vmcnt(11)" ::: "memory"); } \
    __builtin_amdgcn_s_barrier();                                             \
    __builtin_amdgcn_sched_barrier(0);                                        \
    MFMA12(cur);                                                              \
    if ((t) + 1 < KITERS) { CVTA(AC); }                                       \
    __builtin_amdgcn_sched_barrier(0);                                        \
    __builtin_amdgcn_s_barrier();                                             \
    __builtin_amdgcn_sched_barrier(0);                                        \
    if ((t) + 2 < KITERS) { STAGE_B(cur, (t) + 2); }                          \
  }

  float4 aFA[8], aFB[8];
  bf16x8 abf[4];

  // prologue: establish invariant [B(t), A(t+1), B(t+1)] outstanding at loop top
  LOADA(aFA, 0);            // A(0): 8
  STAGE_B(0, 0);            // B(0): 3   -> 11
  LOADA(aFB, 1);            // A(1): 8   -> 19
  asm volatile("s_waitcnt vmcnt(11)" ::: "memory");   // retire A(0)
  CVTA(aFA);                // abf = A(0), no wait
  STAGE_B(1, 1);            // B(1): 3   -> [B0,A1,B1] = 14

  for (int tt = 0; tt < KITERS; tt += 2) {
    BODY(tt,     aFA, aFB, 0);   // load A(tt+2)->aFA, cvt A(tt+1) from aFB
    BODY(tt + 1, aFB, aFA, 1);   // load A(tt+3)->aFB, cvt A(tt+2) from aFA
  }
#undef STAGE_B
#undef LOADA
#undef CVTA
#undef MFMA12
#undef BODY

  #pragma unroll
  for (int fn = 0; fn < 3; fn++) {
    int col = n * 96 + fn * 32 + (lane & 31);
    #pragma unroll
    for (int reg = 0; reg < 16; reg++) {
      int row = wid * 32 + (reg & 3) + ((reg >> 2) << 3) + ((lane >> 5) << 2);
      z[(row0 + row) * 672 + col] = acc[fn][reg];
    }
  }
}

// ---------- wave-wide f32 sum: 4 DPP levels + ds_swizzle xor16 + shfl xor32 ----------
__device__ __forceinline__ float wave_sum(float v) {
  v += __builtin_bit_cast(float, __builtin_amdgcn_update_dpp(
         0, __builtin_bit_cast(int, v), 0xB1, 0xF, 0xF, true));   // quad_perm xor1
  v += __builtin_bit_cast(float, __builtin_amdgcn_update_dpp(
         0, __builtin_bit_cast(int, v), 0x4E, 0xF, 0xF, true));   // quad_perm xor2
  v += __builtin_bit_cast(float, __builtin_amdgcn_update_dpp(
         0, __builtin_bit_cast(int, v), 0x141, 0xF, 0xF, true));  // row_half_mirror
  v += __builtin_bit_cast(float, __builtin_amdgcn_update_dpp(
         0, __builtin_bit_cast(int, v), 0x140, 0xF, 0xF, true));  // row_mirror
  v += __builtin_bit_cast(float, __builtin_amdgcn_ds_swizzle(
         __builtin_bit_cast(int, v), 0x401F));                    // xor16
  v += __shfl_xor(v, 32);                                         // cross-32
  return v;
}

// ---------- K2: Kuramoto dynamics + in-place scale of d_out ----------
#define ZSTR 164
#define DROWS 32
__launch_bounds__(256, 6)
__global__ void dyn_scale(float* __restrict__ z,
                          const float* __restrict__ pdt_p,
                          const float* __restrict__ ptg_p) {
  __shared__ float zdt[DROWS * ZSTR];
  __shared__ float Fbuf[2 * DROWS];
  const int tid = threadIdx.x;
  const int wid = tid >> 6, lane = tid & 63;
  const size_t row0 = (size_t)blockIdx.x * DROWS;

  for (int i = tid; i < DROWS * 40; i += 256) {
    int row = i / 40, c4 = i - row * 40;
    float4 v = *(const float4*)(z + (row0 + row) * 672 + c4 * 4);
    *(float4*)(&zdt[row * ZSTR + c4 * 4]) = v;
  }
  __syncthreads();

  const float pdt = fminf(fmaxf(pdt_p[0], 0.f), 1.f);
  const float ptg = fminf(fmaxf(ptg_p[0], 0.f), 1.f);

  for (int rr = 0; rr < 8; rr++) {
    int row = wid * 8 + rr;
    // phases in revolutions: q = p / 2π;  sin(p) = v_sin(fract(q))
    float pd  = ((lane < 32) ? zdt[row * ZSTR + lane] : 0.f) * INV_2PI_F;
    float pt0 = zdt[row * ZSTR + 32 + lane] * INV_2PI_F;
    float pt1 = zdt[row * ZSTR + 96 + lane] * INV_2PI_F;
    float Ft = 1.f, Fg = 1.f;
    for (int s = 0; s < 10; s++) {
      float qd = pd - floorf(pd), q0 = pt0 - floorf(pt0), q1 = pt1 - floorf(pt1);
      float sd, cd, s0, c0, s1, c1;
      asm("v_sin_f32 %0, %1" : "=v"(sd) : "v"(qd));
      asm("v_cos_f32 %0, %1" : "=v"(cd) : "v"(qd));
      asm("v_sin_f32 %0, %1" : "=v"(s0) : "v"(q0));
      asm("v_cos_f32 %0, %1" : "=v"(c0) : "v"(q0));
      asm("v_sin_f32 %0, %1" : "=v"(s1) : "v"(q1));
      asm("v_cos_f32 %0, %1" : "=v"(c1) : "v"(q1));
      float Cd = wave_sum((lane < 32) ? cd : 0.f) * (1.f / 32.f);
      float Sd = wave_sum((lane < 32) ? sd : 0.f) * (1.f / 32.f);
      float Ct = wave_sum(c0 + c1) * (1.f / 128.f);
      float St = wave_sum(s0 + s1) * (1.f / 128.f);
      pd  += DTF * 2.f + CPL * (Sd * cd - Cd * sd);
      pt0 += DTF * 6.f + CPL * (St * c0 - Ct * s0);
      pt1 += DTF * 6.f + CPL * (St * c1 - Ct * s1);
      float rdm = sqrtf(Cd * Cd + Sd * Sd) + EPSF;
      float rtm = sqrtf(Ct * Ct + St * St) + EPSF;
      Ft *= (1.f + DTF * pdt * (Cd / rdm));
      Fg *= (1.f + DTF * ptg * (Ct / rtm));
    }
    if (lane == 0) { Fbuf[row] = Ft; Fbuf[DROWS + row] = Fg; }
  }
  __syncthreads();

  for (int i = tid; i < DROWS * 168; i += 256) {
    int row = i / 168, c4 = i - row * 168;
    float4* p = (float4*)(z + (row0 + row) * 672 + c4 * 4);
    float4 v = *p;
    float f = (c4 < 8) ? 1.f : (c4 < 40 ? Fbuf[row] : Fbuf[DROWS + row]);
    v.x = fmaxf(fmaxf(fabsf(v.x), EPSF) * f, EPSF);
    v.y = fmaxf(fmaxf(fabsf(v.y), EPSF) * f, EPSF);
    v.z = fmaxf(fmaxf(fabsf(v.z), EPSF) * f, EPSF);
    v.w = fmaxf(fmaxf(fabsf(v.w), EPSF) * f, EPSF);
    *p = v;
  }
}

extern "C" void kernel_launch(void* const* d_in, const int* in_sizes, int n_in,
                              void* d_out, int out_size, void* d_ws, size_t ws_size,
                              hipStream_t stream) {
  const float* x   = (const float*)d_in[0];
  const float* Wd  = (const float*)d_in[1];
  const float* Wt  = (const float*)d_in[2];
  const float* Wg  = (const float*)d_in[3];
  const float* pdt = (const float*)d_in[4];
  const float* ptg = (const float*)d_in[5];
  float* outp = (float*)d_out;
  char* wbB = (char*)d_ws;

  if (ws_size < WS_NEED) return;

  const int Brows = in_sizes[0] / 2048;           // 32768
  prep_w<<<(672 * 64 + 255) / 256, 256, 0, stream>>>(Wd, Wt, Wg, wbB);
  gemm_f<<<(Brows / BM) * NTILES, 256, 0, stream>>>(x, wbB, outp);
  dyn_scale<<<Brows / DROWS, 256, 0, stream>>>(outp, pdt, ptg);
}